// Round 7
// baseline (248.647 us; speedup 1.0000x reference)
//
#include <hip/hip_runtime.h>

// ---------------------------------------------------------------------------
// GraphConvpoolMPNN fused rewrite. bs=16,S=17,N=256,F=64,MW=2 -> 256 windows,
// N1=512. adj2@xb == adj@(adj@xb); scores recomputed per hop. Two hop
// kernels (R14 split): 512 thr / 8 waves / 32 rows per wave, 2 WGs per
// window. R14 killed the spill (WRITE = algorithmic 16.6MB, VGPR 112/256
// budget) but left both hops latency-bound: no pipe >44%, occupancy 19%,
// unroll-1 c-loop = one serial dep chain per iteration with 2 waves/SIMD.
// R15: (a) FULL unroll of the c-loop (the unroll-1 clamp was a spill-era
// holdover; at 256-reg budget the ~160-reg live set has room) -> compiler
// software-pipelines LDS reads across iterations, overlaps softmax VALU with
// MFMA, constant-folds the per-iteration XOR-swizzle address math. (b) z1
// moves between hops as a raw swizzled slab2 IMAGE: k_h1 writes z1T into
// slab2 (old k_mega pass-0 pattern, bit-identical) + vector-dumps its half;
// k_h2 block-copies image->slab2 with 8 u32x4/thread, zero address math
// (replaces 64 scalar global u16 loads/thread + transpose addressing).
// Spill tripwire for next round: WRITE > 30MB on either hop = unroll
// re-spilled -> back off to unroll 2.
// Pipeline: k_prep -> k_y (x@W^T + BN0 stats) -> k_h1 (scores/softmax/hop1
//   -> z1T image) -> k_h2 (scores/softmax/hop2/projection + BN1 stats)
//   -> k_final (BN1 + lrelu + mean).
// ---------------------------------------------------------------------------

typedef unsigned short u16;
typedef __bf16 bf16x8 __attribute__((ext_vector_type(8)));
typedef float f32x4 __attribute__((ext_vector_type(4)));
typedef unsigned int u32x4 __attribute__((ext_vector_type(4)));

#define MFMA16(a, b, c) __builtin_amdgcn_mfma_f32_16x16x32_bf16(a, b, c, 0, 0, 0)

#define BSZ 16
#define SNUM 17
#define FD 64
#define NB 256
#define N1 512
#define SL_ELEMS 16384
#define Y_ELEMS (BSZ * SNUM * SL_ELEMS)

// canonical param buffer offsets (u16 elements)
#define WM_O 0
#define BM_O 4096
#define B0W_O 4160
#define B0B_O 4224
#define T0W_O 4288
#define T0B_O 8384
#define T1W_O 8448
#define T1B_O 12544
#define B1W_O 12608
#define B1B_O 12672
#define P_TOT 12736

// hop-kernel LDS map (u16 units): slab1 [512][64] XOR, slab2 [64][512] XOR,
// red 128 floats (256 u16), scr 8 waves x (16 rows x 40)
#define SLAB2_O 32768
#define RED_O 65536
#define SCR_O 65792
#define LDS_U16 (SCR_O + 8 * 640)  // 70,912 u16 = 141,824 B -> 1 WG/CU

__device__ __forceinline__ float bf2f(u16 u) {
    union { unsigned int i; float f; } v;
    v.i = ((unsigned int)u) << 16;
    return v.f;
}
__device__ __forceinline__ u16 f2bu(float f) {  // RNE via HW cvt
    __bf16 h = (__bf16)f;
    return __builtin_bit_cast(u16, h);
}
__device__ __forceinline__ u16 f2bf(float f) {  // manual RNE (canon path)
    unsigned int u = __builtin_bit_cast(unsigned int, f);
    unsigned int r = (u + 0x7fffu + ((u >> 16) & 1u)) >> 16;
    return (u16)r;
}
__device__ __forceinline__ bf16x8 ld8g(const u16* p) {
    return __builtin_bit_cast(bf16x8, *reinterpret_cast<const u32x4*>(p));
}

// ---------------- prep: dtype detect + canon params + zero stats -----------
__global__ __launch_bounds__(256) void k_prep(
    const void* p0, const void* p1, const void* p2, const void* p3,
    const void* p4, const void* p5, const void* p6, const void* p7,
    const void* p8, const void* p9, int* __restrict__ flagOut,
    u16* __restrict__ pc, float* __restrict__ stats) {
    const int tid = threadIdx.x, lane = tid & 63;
    int z = 0, bc = 0;
    const unsigned int* w = (const unsigned int*)p0;
    for (int i = lane; i < 2048; i += 64) {
        const unsigned int v = w[i];
        z += ((v & 0xffffu) == 0u);
        bc += (v >> 14) & 1;
    }
#pragma unroll
    for (int o = 1; o < 64; o <<= 1) {
        z += __shfl_xor(z, o);
        bc += __shfl_xor(bc, o);
    }
    const int flag = (z > 1024 || bc > 256) ? 1 : 0;
    if (blockIdx.x == 0) {
        if (tid == 0) *flagOut = flag;
        if (tid < 256) stats[tid] = 0.f;
    }
    const int i = blockIdx.x * 256 + tid;
    if (i >= P_TOT) return;
    const void* src;
    int si;
    if (i < BM_O)        { src = p0; si = i; }
    else if (i < B0W_O)  { src = p1; si = i - BM_O; }
    else if (i < B0B_O)  { src = p2; si = i - B0W_O; }
    else if (i < T0W_O)  { src = p3; si = i - B0B_O; }
    else if (i < T0B_O)  { src = p4; si = i - T0W_O; }
    else if (i < T1W_O)  { src = p5; si = i - T0B_O; }
    else if (i < T1B_O)  { src = p6; si = i - T1W_O; }
    else if (i < B1W_O)  { src = p7; si = i - T1B_O; }
    else if (i < B1B_O)  { src = p8; si = i - B1W_O; }
    else                 { src = p9; si = i - B1B_O; }
    pc[i] = flag ? f2bf(((const float*)src)[si]) : ((const u16*)src)[si];
}

// ------------------- y = x @ W^T + b  (+ fused BN0 stats) ------------------
__global__ __launch_bounds__(256) void k_y(const void* __restrict__ xv,
                                           const int* __restrict__ flag,
                                           const u16* __restrict__ pc,
                                           u16* __restrict__ y,
                                           float* __restrict__ gstats) {
    const int slice = blockIdx.x;  // 272
    const int tid = threadIdx.x, wave = tid >> 6, lane = tid & 63;
    const int quad = lane >> 4, l16 = lane & 15;
    __shared__ float red[128];
    if (tid < 128) red[tid] = 0.f;
    const int isf32 = *flag;

    f32x4 acc[4][4];
#pragma unroll
    for (int i = 0; i < 4; i++)
#pragma unroll
        for (int j = 0; j < 4; j++) acc[i][j] = (f32x4){0.f, 0.f, 0.f, 0.f};

    bf16x8 bfr[4][2];
#pragma unroll
    for (int nt = 0; nt < 4; nt++)
#pragma unroll
        for (int kh = 0; kh < 2; kh++)
            bfr[nt][kh] = ld8g(pc + WM_O + (nt * 16 + l16) * 64 + kh * 32 + quad * 8);

    const float* xf = (const float*)xv + (size_t)slice * SL_ELEMS;
    const u16* xh = (const u16*)xv + (size_t)slice * SL_ELEMS;

#pragma unroll
    for (int mt = 0; mt < 4; mt++) {
        const int row = wave * 64 + mt * 16 + l16;
        bf16x8 a0, a1;
        if (isf32) {
            const float* r0 = xf + row * 64 + quad * 8;
            f32x4 v0 = *(const f32x4*)r0;
            f32x4 v1 = *(const f32x4*)(r0 + 4);
            f32x4 v2 = *(const f32x4*)(r0 + 32);
            f32x4 v3 = *(const f32x4*)(r0 + 36);
#pragma unroll
            for (int j = 0; j < 4; j++) {
                a0[j] = (__bf16)v0[j]; a0[4 + j] = (__bf16)v1[j];
                a1[j] = (__bf16)v2[j]; a1[4 + j] = (__bf16)v3[j];
            }
        } else {
            a0 = ld8g(xh + row * 64 + quad * 8);
            a1 = ld8g(xh + row * 64 + 32 + quad * 8);
        }
#pragma unroll
        for (int nt = 0; nt < 4; nt++)
            acc[mt][nt] = MFMA16(a1, bfr[nt][1], MFMA16(a0, bfr[nt][0], acc[mt][nt]));
    }

    u16* ys = y + (size_t)slice * SL_ELEMS;
    float s1[4] = {0.f, 0.f, 0.f, 0.f}, s2[4] = {0.f, 0.f, 0.f, 0.f};
#pragma unroll
    for (int nt = 0; nt < 4; nt++) {
        const int col = nt * 16 + l16;
        const float bias = bf2f(pc[BM_O + col]);
#pragma unroll
        for (int mt = 0; mt < 4; mt++)
#pragma unroll
            for (int r = 0; r < 4; r++) {
                const int row = wave * 64 + mt * 16 + quad * 4 + r;
                const float v = acc[mt][nt][r] + bias;
                ys[row * 64 + col] = f2bu(v);
                s1[nt] += v;
                s2[nt] += v * v;
            }
        s1[nt] += __shfl_xor(s1[nt], 16); s1[nt] += __shfl_xor(s1[nt], 32);
        s2[nt] += __shfl_xor(s2[nt], 16); s2[nt] += __shfl_xor(s2[nt], 32);
    }
    __syncthreads();
    if (quad == 0) {
#pragma unroll
        for (int nt = 0; nt < 4; nt++) {
            atomicAdd(&red[nt * 16 + l16], s1[nt]);
            atomicAdd(&red[64 + nt * 16 + l16], s2[nt]);
        }
    }
    __syncthreads();
    const int s = slice % SNUM;
    const float wgt = (s == 0 || s == SNUM - 1) ? 1.f : 2.f;
    if (tid < 128) atomicAdd(&gstats[tid], red[tid] * wgt);
}

// ---- shared staging helper for the hop kernels (512 thr / 8 waves) --------
__device__ __forceinline__ void stage_slab1(u16* slab1, const u16* ybase,
                                            int tid) {
#pragma unroll
    for (int i = 0; i < 8; i++) {
        const int gid = i * 512 + tid, n = gid >> 3, g = gid & 7;
        *(u32x4*)(slab1 + n * 64 + ((g ^ (n & 7)) << 3)) =
            *(const u32x4*)(ybase + n * 64 + g * 8);
    }
}

// --------------------------- hop 1: z1 = P@xb/l + xb -----------------------
// 512 WGs = 256 windows x 2 halves; 8 waves x 32 rows (2 subtiles).
// Output: z1T as a raw swizzled slab2 image (each WG dumps its own half's
// chunks; positions (gn^f) for gn in [h*32,h*32+32) land at row offset
// ((h*32)^(f&32))*8, length 256 u16).
__global__ __launch_bounds__(512)
__attribute__((amdgpu_waves_per_eu(2, 2)))
void k_h1(const u16* __restrict__ y, const float* __restrict__ stats,
          const u16* __restrict__ pc, u16* __restrict__ z1img) {
    __shared__ u16 lds[LDS_U16];
    u16* slab1 = lds;                       // [n 0..511][g 0..7] XOR(n&7)
    u16* slab2 = lds + SLAB2_O;             // xbT then z1T: [f][gn] XOR(f)
    const int tid = threadIdx.x, w = tid >> 6, lane = tid & 63;
    const int quad = lane >> 4, l16 = lane & 15;
    u16* scr = lds + SCR_O + w * 640;       // 16 rows x 40 u16, per wave
    const int g = blockIdx.x, p = g >> 1, half = g & 1;
    const int b = p >> 4, l = p & 15;
    const f32x4 ZERO4 = (f32x4){0.f, 0.f, 0.f, 0.f};

    // BN0 affine constants (per thread channel fme, for slab2 build)
    const float cinv = 1.f / 131072.f;
    const int fme = tid & 63;
    float mu0 = stats[fme] * cinv;
    float vr0 = fmaxf(stats[64 + fme] * cinv - mu0 * mu0, 0.f);
    const float scale_f = rsqrtf(vr0 + 1e-5f) * bf2f(pc[B0W_O + fme]);
    const float shift_f = bf2f(pc[B0B_O + fme]) - mu0 * scale_f;

    const u16* ybase = y + (size_t)(b * SNUM + l) * SL_ELEMS;
    stage_slab1(slab1, ybase, tid);
    __syncthreads();

    // build slab2 = xbT = BN0(nf) transposed, bf16
#pragma unroll
    for (int i = 0; i < 8; i++) {
        const int gn = w + i * 8;
        union { u16 u[8]; u32x4 v; } pk;
#pragma unroll
        for (int j = 0; j < 8; j++) {
            const int n = gn * 8 + j;
            const u16 raw = slab1[n * 64 + (((fme >> 3) ^ (n & 7)) << 3) + (fme & 7)];
            pk.u[j] = f2bu(bf2f(raw) * scale_f + shift_f);
        }
        *(u32x4*)(slab2 + fme * 512 + ((gn ^ fme) << 3)) = pk.v;
    }
    __syncthreads();

    // hoist nf A-frags for this wave's 32 rows (2 subtiles of 16)
    bf16x8 a[2][2];
#pragma unroll
    for (int st = 0; st < 2; st++)
#pragma unroll
        for (int h = 0; h < 2; h++) {
            const int row = half * 256 + w * 32 + st * 16 + l16;
            a[st][h] = *(const bf16x8*)(slab1 + row * 64 + (((h * 4 + quad) ^ (row & 7)) << 3));
        }

    // decay-mask fold: lsum holds mf-scaled values; boundary+final
    // wave-uniform rescale reconstructs exact denominator.
    const float mb = (half == 0) ? 0.7f : (1.0f / 0.7f);
    const float me = (half == 0) ? (1.0f / 0.7f) : 1.0f;

    f32x4 oacc[2][4];
    f32x4 lsum[2];
#pragma unroll
    for (int st = 0; st < 2; st++) {
        lsum[st] = ZERO4;
#pragma unroll
        for (int ft = 0; ft < 4; ft++) oacc[st][ft] = ZERO4;
    }

#pragma unroll
    for (int c = 0; c < 8; c++) {
        if (c == 4) {
#pragma unroll
            for (int st = 0; st < 2; st++)
#pragma unroll
                for (int r = 0; r < 4; r++) lsum[st][r] *= mb;
        }
        const float lmf = ((half == 1) == (c >= 4)) ? 0.f : -0.5145731728f;
#pragma unroll
        for (int ch = 0; ch < 2; ch++) {
            const int colbase = c * 64 + ch * 32;
            f32x4 S[2][2];
#pragma unroll
            for (int jt = 0; jt < 2; jt++) {
                const int rj = colbase + jt * 16 + l16;
                const bf16x8 b0 = *(const bf16x8*)(slab1 + rj * 64 + ((quad ^ (rj & 7)) << 3));
                const bf16x8 b1 = *(const bf16x8*)(slab1 + rj * 64 + (((4 + quad) ^ (rj & 7)) << 3));
#pragma unroll
                for (int st = 0; st < 2; st++)
                    S[st][jt] = MFMA16(a[st][1], b1, MFMA16(a[st][0], b0, ZERO4));
            }
            bf16x8 pa[2];
#pragma unroll
            for (int st = 0; st < 2; st++) {
                const int rowbase = half * 256 + w * 32 + st * 16;
#pragma unroll
                for (int jt = 0; jt < 2; jt++)
#pragma unroll
                    for (int r = 0; r < 4; r++) {
                        const float s = S[st][jt][r];
                        const float m2 = s > 0.f ? 1.44269504f : 0.0144269504f;
                        float pv = exp2f(fminf(fmaf(s, m2, lmf), 86.f));
                        if (colbase + jt * 16 == rowbase && l16 == quad * 4 + r) pv = 0.f;
                        lsum[st][r] += pv;
                        scr[(quad * 4 + r) * 40 + jt * 16 + l16] = f2bu(pv);
                    }
                pa[st] = *(const bf16x8*)(scr + l16 * 40 + quad * 8);
            }
#pragma unroll
            for (int ft = 0; ft < 4; ft++) {
                const int f = ft * 16 + l16, gn = c * 8 + ch * 4 + quad;
                const bf16x8 bv = *(const bf16x8*)(slab2 + f * 512 + ((gn ^ f) << 3));
                oacc[0][ft] = MFMA16(pa[0], bv, oacc[0][ft]);
                oacc[1][ft] = MFMA16(pa[1], bv, oacc[1][ft]);
            }
        }
    }
    // softmax denominators
#pragma unroll
    for (int st = 0; st < 2; st++)
#pragma unroll
        for (int r = 0; r < 4; r++) {
            lsum[st][r] += __shfl_xor(lsum[st][r], 1);
            lsum[st][r] += __shfl_xor(lsum[st][r], 2);
            lsum[st][r] += __shfl_xor(lsum[st][r], 4);
            lsum[st][r] += __shfl_xor(lsum[st][r], 8);
        }

    // z1 = P@xb / l + xb(own row); keep in oacc
#pragma unroll
    for (int st = 0; st < 2; st++) {
        f32x4 inv;
#pragma unroll
        for (int r = 0; r < 4; r++) inv[r] = __builtin_amdgcn_rcpf(lsum[st][r] * me);
#pragma unroll
        for (int ft = 0; ft < 4; ft++)
#pragma unroll
            for (int r = 0; r < 4; r++) {
                const int i = half * 256 + w * 32 + st * 16 + quad * 4 + r;
                const int f = ft * 16 + l16;
                const float xbv = bf2f(slab2[f * 512 + (((i >> 3) ^ f) << 3) + (i & 7)]);
                oacc[st][ft][r] = oacc[st][ft][r] * inv[r] + xbv;
            }
    }
    __syncthreads();  // all waves done reading xbT (bv + xbv)
    // write z1T into slab2 (overwrite xbT; bit-identical to old k_mega)
#pragma unroll
    for (int st = 0; st < 2; st++)
#pragma unroll
        for (int ft = 0; ft < 4; ft++)
#pragma unroll
            for (int r = 0; r < 4; r++) {
                const int i = half * 256 + w * 32 + st * 16 + quad * 4 + r;
                const int f = ft * 16 + l16;
                slab2[f * 512 + (((i >> 3) ^ f) << 3) + (i & 7)] = f2bu(oacc[st][ft][r]);
            }
    __syncthreads();
    // dump own-half image chunks to global (vector, coalesced)
    {
        const int fr = tid >> 3, seg = tid & 7;
        const int off = (((half * 32) ^ (fr & 32)) << 3) + seg * 32;
        u16* dst = z1img + (size_t)p * 32768 + fr * 512 + off;
        const u16* srcp = slab2 + fr * 512 + off;
#pragma unroll
        for (int k = 0; k < 4; k++)
            *(u32x4*)(dst + k * 8) = *(const u32x4*)(srcp + k * 8);
    }
}

// ------ hop 2: out = z1@w0^T + (P@z1/l + z1)@w1^T + b  (+ BN1 stats) -------
__global__ __launch_bounds__(512)
__attribute__((amdgpu_waves_per_eu(2, 2)))
void k_h2(const u16* __restrict__ y, const u16* __restrict__ z1img,
          float* __restrict__ stats, const u16* __restrict__ pc,
          u16* __restrict__ opre) {
    __shared__ u16 lds[LDS_U16];
    u16* slab1 = lds;                       // nf  [n][g] XOR(n&7)
    u16* slab2 = lds + SLAB2_O;             // z1T [f][gn] XOR(f)
    float* red = (float*)(lds + RED_O);
    const int tid = threadIdx.x, w = tid >> 6, lane = tid & 63;
    const int quad = lane >> 4, l16 = lane & 15;
    u16* scr = lds + SCR_O + w * 640;
    const int g = blockIdx.x, p = g >> 1, half = g & 1;
    const int b = p >> 4, l = p & 15;
    const f32x4 ZERO4 = (f32x4){0.f, 0.f, 0.f, 0.f};

    if (tid < 128) red[tid] = 0.f;

    const u16* ybase = y + (size_t)(b * SNUM + l) * SL_ELEMS;
    stage_slab1(slab1, ybase, tid);

    // slab2 <- z1T raw image (block copy, zero address math)
    const u16* zsrc = z1img + (size_t)p * 32768;
#pragma unroll
    for (int i = 0; i < 8; i++) {
        const int gid = i * 512 + tid;
        *(u32x4*)(slab2 + gid * 8) = *(const u32x4*)(zsrc + gid * 8);
    }
    __syncthreads();

    bf16x8 a[2][2];
#pragma unroll
    for (int st = 0; st < 2; st++)
#pragma unroll
        for (int h = 0; h < 2; h++) {
            const int row = half * 256 + w * 32 + st * 16 + l16;
            a[st][h] = *(const bf16x8*)(slab1 + row * 64 + (((h * 4 + quad) ^ (row & 7)) << 3));
        }

    const float mb = (half == 0) ? 0.7f : (1.0f / 0.7f);
    const float me = (half == 0) ? (1.0f / 0.7f) : 1.0f;

    f32x4 oacc[2][4];
    f32x4 lsum[2];
#pragma unroll
    for (int st = 0; st < 2; st++) {
        lsum[st] = ZERO4;
#pragma unroll
        for (int ft = 0; ft < 4; ft++) oacc[st][ft] = ZERO4;
    }

#pragma unroll
    for (int c = 0; c < 8; c++) {
        if (c == 4) {
#pragma unroll
            for (int st = 0; st < 2; st++)
#pragma unroll
                for (int r = 0; r < 4; r++) lsum[st][r] *= mb;
        }
        const float lmf = ((half == 1) == (c >= 4)) ? 0.f : -0.5145731728f;
#pragma unroll
        for (int ch = 0; ch < 2; ch++) {
            const int colbase = c * 64 + ch * 32;
            f32x4 S[2][2];
#pragma unroll
            for (int jt = 0; jt < 2; jt++) {
                const int rj = colbase + jt * 16 + l16;
                const bf16x8 b0 = *(const bf16x8*)(slab1 + rj * 64 + ((quad ^ (rj & 7)) << 3));
                const bf16x8 b1 = *(const bf16x8*)(slab1 + rj * 64 + (((4 + quad) ^ (rj & 7)) << 3));
#pragma unroll
                for (int st = 0; st < 2; st++)
                    S[st][jt] = MFMA16(a[st][1], b1, MFMA16(a[st][0], b0, ZERO4));
            }
            bf16x8 pa[2];
#pragma unroll
            for (int st = 0; st < 2; st++) {
                const int rowbase = half * 256 + w * 32 + st * 16;
#pragma unroll
                for (int jt = 0; jt < 2; jt++)
#pragma unroll
                    for (int r = 0; r < 4; r++) {
                        const float s = S[st][jt][r];
                        const float m2 = s > 0.f ? 1.44269504f : 0.0144269504f;
                        float pv = exp2f(fminf(fmaf(s, m2, lmf), 86.f));
                        if (colbase + jt * 16 == rowbase && l16 == quad * 4 + r) pv = 0.f;
                        lsum[st][r] += pv;
                        scr[(quad * 4 + r) * 40 + jt * 16 + l16] = f2bu(pv);
                    }
                pa[st] = *(const bf16x8*)(scr + l16 * 40 + quad * 8);
            }
#pragma unroll
            for (int ft = 0; ft < 4; ft++) {
                const int f = ft * 16 + l16, gn = c * 8 + ch * 4 + quad;
                const bf16x8 bv = *(const bf16x8*)(slab2 + f * 512 + ((gn ^ f) << 3));
                oacc[0][ft] = MFMA16(pa[0], bv, oacc[0][ft]);
                oacc[1][ft] = MFMA16(pa[1], bv, oacc[1][ft]);
            }
        }
    }
#pragma unroll
    for (int st = 0; st < 2; st++)
#pragma unroll
        for (int r = 0; r < 4; r++) {
            lsum[st][r] += __shfl_xor(lsum[st][r], 1);
            lsum[st][r] += __shfl_xor(lsum[st][r], 2);
            lsum[st][r] += __shfl_xor(lsum[st][r], 4);
            lsum[st][r] += __shfl_xor(lsum[st][r], 8);
        }

    // out2 = P@z1/l + z1(own); fused projection + BN1 partials
    float s1a[4] = {0.f, 0.f, 0.f, 0.f}, s2a[4] = {0.f, 0.f, 0.f, 0.f};
#pragma unroll
    for (int st = 0; st < 2; st++) {
        f32x4 inv;
#pragma unroll
        for (int r = 0; r < 4; r++) inv[r] = __builtin_amdgcn_rcpf(lsum[st][r] * me);
#pragma unroll
        for (int ft = 0; ft < 4; ft++)
#pragma unroll
            for (int r = 0; r < 4; r++) {
                const int i = half * 256 + w * 32 + st * 16 + quad * 4 + r;
                const int f = ft * 16 + l16;
                const float o1 = bf2f(slab2[f * 512 + (((i >> 3) ^ f) << 3) + (i & 7)]);
                oacc[st][ft][r] = oacc[st][ft][r] * inv[r] + o1;
            }
        // a1 = z1 A-frag (from z1T slab, scalar gather)
        bf16x8 a1[2], a2[2];
        const int irow = half * 256 + w * 32 + st * 16 + l16;
#pragma unroll
        for (int h = 0; h < 2; h++)
#pragma unroll
            for (int j = 0; j < 8; j++) {
                const int f = h * 32 + quad * 8 + j;
                const u16 raw = slab2[f * 512 + (((irow >> 3) ^ f) << 3) + (irow & 7)];
                a1[h][j] = __builtin_bit_cast(__bf16, raw);
            }
        // a2 = out2 A-frag via per-wave scratch
#pragma unroll
        for (int h = 0; h < 2; h++) {
#pragma unroll
            for (int ftl = 0; ftl < 2; ftl++)
#pragma unroll
                for (int r = 0; r < 4; r++)
                    scr[(quad * 4 + r) * 40 + ftl * 16 + l16] = f2bu(oacc[st][2 * h + ftl][r]);
            a2[h] = *(const bf16x8*)(scr + l16 * 40 + quad * 8);
        }
        f32x4 pacc[4];
#pragma unroll
        for (int ot = 0; ot < 4; ot++) {
            const int o = ot * 16 + l16;
            const float bias = bf2f(pc[T0B_O + o]) + bf2f(pc[T1B_O + o]);
            pacc[ot] = (f32x4){bias, bias, bias, bias};
        }
#pragma unroll
        for (int h = 0; h < 2; h++)
#pragma unroll
            for (int ot = 0; ot < 4; ot++) {
                const int o = ot * 16 + l16;
                bf16x8 w0f = ld8g(pc + T0W_O + o * 64 + h * 32 + quad * 8);
                bf16x8 w1f = ld8g(pc + T1W_O + o * 64 + h * 32 + quad * 8);
                pacc[ot] = MFMA16(a1[h], w0f, pacc[ot]);
                pacc[ot] = MFMA16(a2[h], w1f, pacc[ot]);
            }
#pragma unroll
        for (int ot = 0; ot < 4; ot++)
#pragma unroll
            for (int r = 0; r < 4; r++) {
                const int i = half * 256 + w * 32 + st * 16 + quad * 4 + r;
                const int o = ot * 16 + l16;
                const float v = pacc[ot][r];
                s1a[ot] += v;
                s2a[ot] += v * v;
                opre[(size_t)p * (N1 * FD) + (size_t)i * 64 + o] = f2bu(v);
            }
    }
#pragma unroll
    for (int ot = 0; ot < 4; ot++) {
        s1a[ot] += __shfl_xor(s1a[ot], 16); s1a[ot] += __shfl_xor(s1a[ot], 32);
        s2a[ot] += __shfl_xor(s2a[ot], 16); s2a[ot] += __shfl_xor(s2a[ot], 32);
    }
    if (quad == 0) {
#pragma unroll
        for (int ot = 0; ot < 4; ot++) {
            atomicAdd(&red[ot * 16 + l16], s1a[ot]);
            atomicAdd(&red[64 + ot * 16 + l16], s2a[ot]);
        }
    }
    __syncthreads();
    if (tid < 128) atomicAdd(&stats[128 + tid], red[tid]);
}

// --------------------------- BN1 + lrelu + pooling -> fp32 out -------------
__global__ __launch_bounds__(256) void k_final(const u16* __restrict__ op,
                                               const float* __restrict__ stats,
                                               const u16* __restrict__ pc,
                                               float* __restrict__ out) {
    const int o = blockIdx.x * 256 + threadIdx.x;
    const int f = o & 63, n = (o >> 6) & 255, b = o >> 14;
    const float inv = 1.f / 131072.f;
    const float mu = stats[128 + f] * inv;
    const float var = fmaxf(stats[192 + f] * inv - mu * mu, 0.f);
    const float rs = rsqrtf(var + 1e-5f);
    const float scale = rs * bf2f(pc[B1W_O + f]);
    const float shift = bf2f(pc[B1B_O + f]) - mu * scale;
    float acc = 0.f;
    for (int l = 0; l < 16; l++) {
        const size_t pb = (size_t)(b * 16 + l) * N1 * FD;
#pragma unroll
        for (int m = 0; m < 2; m++) {
            float v = bf2f(op[pb + (size_t)(m * 256 + n) * 64 + f]);
            v = v * scale + shift;
            acc += (v > 0.f ? v : 0.01f * v);
        }
    }
    out[o] = acc * (1.f / 32.f);
}

// ---------------------------------------------------------------------------
extern "C" void kernel_launch(void* const* d_in, const int* in_sizes, int n_in,
                              void* d_out, int out_size, void* d_ws, size_t ws_size,
                              hipStream_t stream) {
    char* ws = (char*)d_ws;
    size_t off = 0;
    auto alloc = [&](size_t bytes) { void* pp = ws + off; off += (bytes + 255) & ~(size_t)255; return pp; };
    u16* y = (u16*)alloc((size_t)Y_ELEMS * 2);
    u16* z1img = (u16*)alloc((size_t)NB * 32768 * 2);
    u16* opre = (u16*)alloc((size_t)NB * N1 * FD * 2);
    u16* pc = (u16*)alloc(P_TOT * 2);
    float* stats = (float*)alloc(256 * 4);
    int* flag = (int*)alloc(256);
    float* out = (float*)d_out;

    k_prep<<<50, 256, 0, stream>>>(d_in[1], d_in[2], d_in[3], d_in[4], d_in[5],
                                   d_in[6], d_in[7], d_in[8], d_in[9], d_in[10],
                                   flag, pc, stats);
    k_y<<<BSZ * SNUM, 256, 0, stream>>>(d_in[0], flag, pc, y, stats);
    k_h1<<<2 * NB, 512, 0, stream>>>(y, stats, pc, z1img);
    k_h2<<<2 * NB, 512, 0, stream>>>(y, z1img, stats, pc, opre);
    k_final<<<1024, 256, 0, stream>>>(opre, stats, pc, out);
}

// Round 8
// 210.249 us; speedup vs baseline: 1.1826x; 1.1826x over previous
//
#include <hip/hip_runtime.h>

// ---------------------------------------------------------------------------
// GraphConvpoolMPNN fused rewrite. bs=16,S=17,N=256,F=64,MW=2 -> 256 windows,
// N1=512. adj2@xb == adj@(adj@xb); scores recomputed per hop. Two hop
// kernels (R14 split). R16: WG geometry that satisfies BOTH walls mapped in
// R8-R15: (reg wall) 32-rows/wave needs ~160 regs -> spills at the 128-reg
// budget of 4 waves/SIMD; (latency wall) 2 waves/SIMD is latency-bound.
// 16 rows/wave halves the live set to ~100 regs < 128 -> 1024 thr / 16
// waves / 16 rows per wave / 2 WGs per window: 4 waves/SIMD occupancy AND
// no spill. unroll 1 on c restored (R15's full unroll re-spilled: WRITE
// 68.6 vs 16.8 MB algorithmic); z1 moves as a raw swizzled slab2 image
// (vector block copy, zero address math - kept from R15, it was clean).
// All register-array-indexing loops fully unrolled (R11/R12 lesson).
// Spill tripwire: WRITE > 30MB on either hop.
// Pipeline: k_prep -> k_y (x@W^T + BN0 stats) -> k_h1 (scores/softmax/hop1
//   -> z1T image) -> k_h2 (scores/softmax/hop2/projection + BN1 stats)
//   -> k_final (BN1 + lrelu + mean).
// ---------------------------------------------------------------------------

typedef unsigned short u16;
typedef __bf16 bf16x8 __attribute__((ext_vector_type(8)));
typedef float f32x4 __attribute__((ext_vector_type(4)));
typedef unsigned int u32x4 __attribute__((ext_vector_type(4)));

#define MFMA16(a, b, c) __builtin_amdgcn_mfma_f32_16x16x32_bf16(a, b, c, 0, 0, 0)

#define BSZ 16
#define SNUM 17
#define FD 64
#define NB 256
#define N1 512
#define SL_ELEMS 16384
#define Y_ELEMS (BSZ * SNUM * SL_ELEMS)

// canonical param buffer offsets (u16 elements)
#define WM_O 0
#define BM_O 4096
#define B0W_O 4160
#define B0B_O 4224
#define T0W_O 4288
#define T0B_O 8384
#define T1W_O 8448
#define T1B_O 12544
#define B1W_O 12608
#define B1B_O 12672
#define P_TOT 12736

// hop-kernel LDS map (u16 units): slab1 [512][64] XOR, slab2 [64][512] XOR,
// red 128 floats (256 u16), scr 16 waves x (16 rows x 40)
#define SLAB2_O 32768
#define RED_O 65536
#define SCR_O 65792
#define LDS_U16 (SCR_O + 16 * 640)  // 76,032 u16 = 152,064 B -> 1 WG/CU

__device__ __forceinline__ float bf2f(u16 u) {
    union { unsigned int i; float f; } v;
    v.i = ((unsigned int)u) << 16;
    return v.f;
}
__device__ __forceinline__ u16 f2bu(float f) {  // RNE via HW cvt
    __bf16 h = (__bf16)f;
    return __builtin_bit_cast(u16, h);
}
__device__ __forceinline__ u16 f2bf(float f) {  // manual RNE (canon path)
    unsigned int u = __builtin_bit_cast(unsigned int, f);
    unsigned int r = (u + 0x7fffu + ((u >> 16) & 1u)) >> 16;
    return (u16)r;
}
__device__ __forceinline__ bf16x8 ld8g(const u16* p) {
    return __builtin_bit_cast(bf16x8, *reinterpret_cast<const u32x4*>(p));
}

// ---------------- prep: dtype detect + canon params + zero stats -----------
__global__ __launch_bounds__(256) void k_prep(
    const void* p0, const void* p1, const void* p2, const void* p3,
    const void* p4, const void* p5, const void* p6, const void* p7,
    const void* p8, const void* p9, int* __restrict__ flagOut,
    u16* __restrict__ pc, float* __restrict__ stats) {
    const int tid = threadIdx.x, lane = tid & 63;
    int z = 0, bc = 0;
    const unsigned int* w = (const unsigned int*)p0;
    for (int i = lane; i < 2048; i += 64) {
        const unsigned int v = w[i];
        z += ((v & 0xffffu) == 0u);
        bc += (v >> 14) & 1;
    }
#pragma unroll
    for (int o = 1; o < 64; o <<= 1) {
        z += __shfl_xor(z, o);
        bc += __shfl_xor(bc, o);
    }
    const int flag = (z > 1024 || bc > 256) ? 1 : 0;
    if (blockIdx.x == 0) {
        if (tid == 0) *flagOut = flag;
        if (tid < 256) stats[tid] = 0.f;
    }
    const int i = blockIdx.x * 256 + tid;
    if (i >= P_TOT) return;
    const void* src;
    int si;
    if (i < BM_O)        { src = p0; si = i; }
    else if (i < B0W_O)  { src = p1; si = i - BM_O; }
    else if (i < B0B_O)  { src = p2; si = i - B0W_O; }
    else if (i < T0W_O)  { src = p3; si = i - B0B_O; }
    else if (i < T0B_O)  { src = p4; si = i - T0W_O; }
    else if (i < T1W_O)  { src = p5; si = i - T0B_O; }
    else if (i < T1B_O)  { src = p6; si = i - T1W_O; }
    else if (i < B1W_O)  { src = p7; si = i - T1B_O; }
    else if (i < B1B_O)  { src = p8; si = i - B1W_O; }
    else                 { src = p9; si = i - B1B_O; }
    pc[i] = flag ? f2bf(((const float*)src)[si]) : ((const u16*)src)[si];
}

// ------------------- y = x @ W^T + b  (+ fused BN0 stats) ------------------
__global__ __launch_bounds__(256) void k_y(const void* __restrict__ xv,
                                           const int* __restrict__ flag,
                                           const u16* __restrict__ pc,
                                           u16* __restrict__ y,
                                           float* __restrict__ gstats) {
    const int slice = blockIdx.x;  // 272
    const int tid = threadIdx.x, wave = tid >> 6, lane = tid & 63;
    const int quad = lane >> 4, l16 = lane & 15;
    __shared__ float red[128];
    if (tid < 128) red[tid] = 0.f;
    const int isf32 = *flag;

    f32x4 acc[4][4];
#pragma unroll
    for (int i = 0; i < 4; i++)
#pragma unroll
        for (int j = 0; j < 4; j++) acc[i][j] = (f32x4){0.f, 0.f, 0.f, 0.f};

    bf16x8 bfr[4][2];
#pragma unroll
    for (int nt = 0; nt < 4; nt++)
#pragma unroll
        for (int kh = 0; kh < 2; kh++)
            bfr[nt][kh] = ld8g(pc + WM_O + (nt * 16 + l16) * 64 + kh * 32 + quad * 8);

    const float* xf = (const float*)xv + (size_t)slice * SL_ELEMS;
    const u16* xh = (const u16*)xv + (size_t)slice * SL_ELEMS;

#pragma unroll
    for (int mt = 0; mt < 4; mt++) {
        const int row = wave * 64 + mt * 16 + l16;
        bf16x8 a0, a1;
        if (isf32) {
            const float* r0 = xf + row * 64 + quad * 8;
            f32x4 v0 = *(const f32x4*)r0;
            f32x4 v1 = *(const f32x4*)(r0 + 4);
            f32x4 v2 = *(const f32x4*)(r0 + 32);
            f32x4 v3 = *(const f32x4*)(r0 + 36);
#pragma unroll
            for (int j = 0; j < 4; j++) {
                a0[j] = (__bf16)v0[j]; a0[4 + j] = (__bf16)v1[j];
                a1[j] = (__bf16)v2[j]; a1[4 + j] = (__bf16)v3[j];
            }
        } else {
            a0 = ld8g(xh + row * 64 + quad * 8);
            a1 = ld8g(xh + row * 64 + 32 + quad * 8);
        }
#pragma unroll
        for (int nt = 0; nt < 4; nt++)
            acc[mt][nt] = MFMA16(a1, bfr[nt][1], MFMA16(a0, bfr[nt][0], acc[mt][nt]));
    }

    u16* ys = y + (size_t)slice * SL_ELEMS;
    float s1[4] = {0.f, 0.f, 0.f, 0.f}, s2[4] = {0.f, 0.f, 0.f, 0.f};
#pragma unroll
    for (int nt = 0; nt < 4; nt++) {
        const int col = nt * 16 + l16;
        const float bias = bf2f(pc[BM_O + col]);
#pragma unroll
        for (int mt = 0; mt < 4; mt++)
#pragma unroll
            for (int r = 0; r < 4; r++) {
                const int row = wave * 64 + mt * 16 + quad * 4 + r;
                const float v = acc[mt][nt][r] + bias;
                ys[row * 64 + col] = f2bu(v);
                s1[nt] += v;
                s2[nt] += v * v;
            }
        s1[nt] += __shfl_xor(s1[nt], 16); s1[nt] += __shfl_xor(s1[nt], 32);
        s2[nt] += __shfl_xor(s2[nt], 16); s2[nt] += __shfl_xor(s2[nt], 32);
    }
    __syncthreads();
    if (quad == 0) {
#pragma unroll
        for (int nt = 0; nt < 4; nt++) {
            atomicAdd(&red[nt * 16 + l16], s1[nt]);
            atomicAdd(&red[64 + nt * 16 + l16], s2[nt]);
        }
    }
    __syncthreads();
    const int s = slice % SNUM;
    const float wgt = (s == 0 || s == SNUM - 1) ? 1.f : 2.f;
    if (tid < 128) atomicAdd(&gstats[tid], red[tid] * wgt);
}

// ---- shared staging helper for the hop kernels (1024 thr / 16 waves) ------
__device__ __forceinline__ void stage_slab1(u16* slab1, const u16* ybase,
                                            int tid) {
#pragma unroll
    for (int i = 0; i < 4; i++) {
        const int gid = i * 1024 + tid, n = gid >> 3, g = gid & 7;
        *(u32x4*)(slab1 + n * 64 + ((g ^ (n & 7)) << 3)) =
            *(const u32x4*)(ybase + n * 64 + g * 8);
    }
}

// --------------------------- hop 1: z1 = P@xb/l + xb -----------------------
// 512 WGs = 256 windows x 2 halves; 16 waves x 16 rows (1 subtile each).
// Output: z1T as a raw swizzled slab2 image.
__global__ __launch_bounds__(1024)
__attribute__((amdgpu_waves_per_eu(4, 4)))
void k_h1(const u16* __restrict__ y, const float* __restrict__ stats,
          const u16* __restrict__ pc, u16* __restrict__ z1img) {
    __shared__ u16 lds[LDS_U16];
    u16* slab1 = lds;                       // [n 0..511][g 0..7] XOR(n&7)
    u16* slab2 = lds + SLAB2_O;             // xbT then z1T: [f][gn] XOR(f)
    const int tid = threadIdx.x, w = tid >> 6, lane = tid & 63;
    const int quad = lane >> 4, l16 = lane & 15;
    u16* scr = lds + SCR_O + w * 640;       // 16 rows x 40 u16, per wave
    const int g = blockIdx.x, p = g >> 1, half = g & 1;
    const int b = p >> 4, l = p & 15;
    const f32x4 ZERO4 = (f32x4){0.f, 0.f, 0.f, 0.f};

    // BN0 affine constants (per thread channel fme, for slab2 build)
    const float cinv = 1.f / 131072.f;
    const int fme = tid & 63;
    float mu0 = stats[fme] * cinv;
    float vr0 = fmaxf(stats[64 + fme] * cinv - mu0 * mu0, 0.f);
    const float scale_f = rsqrtf(vr0 + 1e-5f) * bf2f(pc[B0W_O + fme]);
    const float shift_f = bf2f(pc[B0B_O + fme]) - mu0 * scale_f;

    const u16* ybase = y + (size_t)(b * SNUM + l) * SL_ELEMS;
    stage_slab1(slab1, ybase, tid);
    __syncthreads();

    // build slab2 = xbT = BN0(nf) transposed, bf16
#pragma unroll
    for (int i = 0; i < 4; i++) {
        const int gn = (tid >> 6) + i * 16;
        union { u16 u[8]; u32x4 v; } pk;
#pragma unroll
        for (int j = 0; j < 8; j++) {
            const int n = gn * 8 + j;
            const u16 raw = slab1[n * 64 + (((fme >> 3) ^ (n & 7)) << 3) + (fme & 7)];
            pk.u[j] = f2bu(bf2f(raw) * scale_f + shift_f);
        }
        *(u32x4*)(slab2 + fme * 512 + ((gn ^ fme) << 3)) = pk.v;
    }
    __syncthreads();

    // hoist nf A-frags for this wave's 16 rows (single subtile)
    const int rowbase = half * 256 + w * 16;
    bf16x8 a[2];
#pragma unroll
    for (int h = 0; h < 2; h++) {
        const int row = rowbase + l16;
        a[h] = *(const bf16x8*)(slab1 + row * 64 + (((h * 4 + quad) ^ (row & 7)) << 3));
    }

    // decay-mask fold: lsum holds mf-scaled values; boundary+final
    // wave-uniform rescale reconstructs exact denominator.
    const float mb = (half == 0) ? 0.7f : (1.0f / 0.7f);
    const float me = (half == 0) ? (1.0f / 0.7f) : 1.0f;

    f32x4 oacc[4];
    f32x4 lsum = ZERO4;
#pragma unroll
    for (int ft = 0; ft < 4; ft++) oacc[ft] = ZERO4;

#pragma unroll 1
    for (int c = 0; c < 8; c++) {
        if (c == 4) {
#pragma unroll
            for (int r = 0; r < 4; r++) lsum[r] *= mb;
        }
        const float lmf = ((half == 1) == (c >= 4)) ? 0.f : -0.5145731728f;
#pragma unroll
        for (int ch = 0; ch < 2; ch++) {
            const int colbase = c * 64 + ch * 32;
            f32x4 S[2];
#pragma unroll
            for (int jt = 0; jt < 2; jt++) {
                const int rj = colbase + jt * 16 + l16;
                const bf16x8 b0 = *(const bf16x8*)(slab1 + rj * 64 + ((quad ^ (rj & 7)) << 3));
                const bf16x8 b1 = *(const bf16x8*)(slab1 + rj * 64 + (((4 + quad) ^ (rj & 7)) << 3));
                S[jt] = MFMA16(a[1], b1, MFMA16(a[0], b0, ZERO4));
            }
#pragma unroll
            for (int jt = 0; jt < 2; jt++)
#pragma unroll
                for (int r = 0; r < 4; r++) {
                    const float s = S[jt][r];
                    const float m2 = s > 0.f ? 1.44269504f : 0.0144269504f;
                    float pv = exp2f(fminf(fmaf(s, m2, lmf), 86.f));
                    if (colbase + jt * 16 == rowbase && l16 == quad * 4 + r) pv = 0.f;
                    lsum[r] += pv;
                    scr[(quad * 4 + r) * 40 + jt * 16 + l16] = f2bu(pv);
                }
            const bf16x8 pa = *(const bf16x8*)(scr + l16 * 40 + quad * 8);
#pragma unroll
            for (int ft = 0; ft < 4; ft++) {
                const int f = ft * 16 + l16, gn = c * 8 + ch * 4 + quad;
                const bf16x8 bv = *(const bf16x8*)(slab2 + f * 512 + ((gn ^ f) << 3));
                oacc[ft] = MFMA16(pa, bv, oacc[ft]);
            }
        }
    }
    // softmax denominators
#pragma unroll
    for (int r = 0; r < 4; r++) {
        lsum[r] += __shfl_xor(lsum[r], 1);
        lsum[r] += __shfl_xor(lsum[r], 2);
        lsum[r] += __shfl_xor(lsum[r], 4);
        lsum[r] += __shfl_xor(lsum[r], 8);
    }

    // z1 = P@xb / l + xb(own row)
    f32x4 inv;
#pragma unroll
    for (int r = 0; r < 4; r++) inv[r] = __builtin_amdgcn_rcpf(lsum[r] * me);
#pragma unroll
    for (int ft = 0; ft < 4; ft++)
#pragma unroll
        for (int r = 0; r < 4; r++) {
            const int i = rowbase + quad * 4 + r;
            const int f = ft * 16 + l16;
            const float xbv = bf2f(slab2[f * 512 + (((i >> 3) ^ f) << 3) + (i & 7)]);
            oacc[ft][r] = oacc[ft][r] * inv[r] + xbv;
        }
    __syncthreads();  // all waves done reading xbT (bv + xbv)
    // write z1T into slab2 (overwrite xbT; bit-identical to old k_mega)
#pragma unroll
    for (int ft = 0; ft < 4; ft++)
#pragma unroll
        for (int r = 0; r < 4; r++) {
            const int i = rowbase + quad * 4 + r;
            const int f = ft * 16 + l16;
            slab2[f * 512 + (((i >> 3) ^ f) << 3) + (i & 7)] = f2bu(oacc[ft][r]);
        }
    __syncthreads();
    // dump own-half image chunks to global (vector, coalesced):
    // rows gn in [half*32, half*32+32) of row f live at byte-range offset
    // ((half*32)^(f&32))*8, length 256 u16.
    {
        const int fr = tid >> 4, seg = tid & 15;
        const int off = (((half * 32) ^ (fr & 32)) << 3) + seg * 16;
        u16* dst = z1img + (size_t)p * 32768 + fr * 512 + off;
        const u16* srcp = slab2 + fr * 512 + off;
        *(u32x4*)(dst) = *(const u32x4*)(srcp);
        *(u32x4*)(dst + 8) = *(const u32x4*)(srcp + 8);
    }
}

// ------ hop 2: out = z1@w0^T + (P@z1/l + z1)@w1^T + b  (+ BN1 stats) -------
__global__ __launch_bounds__(1024)
__attribute__((amdgpu_waves_per_eu(4, 4)))
void k_h2(const u16* __restrict__ y, const u16* __restrict__ z1img,
          float* __restrict__ stats, const u16* __restrict__ pc,
          u16* __restrict__ opre) {
    __shared__ u16 lds[LDS_U16];
    u16* slab1 = lds;                       // nf  [n][g] XOR(n&7)
    u16* slab2 = lds + SLAB2_O;             // z1T [f][gn] XOR(f)
    float* red = (float*)(lds + RED_O);
    const int tid = threadIdx.x, w = tid >> 6, lane = tid & 63;
    const int quad = lane >> 4, l16 = lane & 15;
    u16* scr = lds + SCR_O + w * 640;
    const int g = blockIdx.x, p = g >> 1, half = g & 1;
    const int b = p >> 4, l = p & 15;
    const f32x4 ZERO4 = (f32x4){0.f, 0.f, 0.f, 0.f};

    if (tid < 128) red[tid] = 0.f;

    const u16* ybase = y + (size_t)(b * SNUM + l) * SL_ELEMS;
    stage_slab1(slab1, ybase, tid);

    // slab2 <- z1T raw image (block copy, zero address math)
    const u16* zsrc = z1img + (size_t)p * 32768;
#pragma unroll
    for (int i = 0; i < 4; i++) {
        const int gid = i * 1024 + tid;
        *(u32x4*)(slab2 + gid * 8) = *(const u32x4*)(zsrc + gid * 8);
    }
    __syncthreads();

    const int rowbase = half * 256 + w * 16;
    bf16x8 a[2];
#pragma unroll
    for (int h = 0; h < 2; h++) {
        const int row = rowbase + l16;
        a[h] = *(const bf16x8*)(slab1 + row * 64 + (((h * 4 + quad) ^ (row & 7)) << 3));
    }

    const float mb = (half == 0) ? 0.7f : (1.0f / 0.7f);
    const float me = (half == 0) ? (1.0f / 0.7f) : 1.0f;

    f32x4 oacc[4];
    f32x4 lsum = ZERO4;
#pragma unroll
    for (int ft = 0; ft < 4; ft++) oacc[ft] = ZERO4;

#pragma unroll 1
    for (int c = 0; c < 8; c++) {
        if (c == 4) {
#pragma unroll
            for (int r = 0; r < 4; r++) lsum[r] *= mb;
        }
        const float lmf = ((half == 1) == (c >= 4)) ? 0.f : -0.5145731728f;
#pragma unroll
        for (int ch = 0; ch < 2; ch++) {
            const int colbase = c * 64 + ch * 32;
            f32x4 S[2];
#pragma unroll
            for (int jt = 0; jt < 2; jt++) {
                const int rj = colbase + jt * 16 + l16;
                const bf16x8 b0 = *(const bf16x8*)(slab1 + rj * 64 + ((quad ^ (rj & 7)) << 3));
                const bf16x8 b1 = *(const bf16x8*)(slab1 + rj * 64 + (((4 + quad) ^ (rj & 7)) << 3));
                S[jt] = MFMA16(a[1], b1, MFMA16(a[0], b0, ZERO4));
            }
#pragma unroll
            for (int jt = 0; jt < 2; jt++)
#pragma unroll
                for (int r = 0; r < 4; r++) {
                    const float s = S[jt][r];
                    const float m2 = s > 0.f ? 1.44269504f : 0.0144269504f;
                    float pv = exp2f(fminf(fmaf(s, m2, lmf), 86.f));
                    if (colbase + jt * 16 == rowbase && l16 == quad * 4 + r) pv = 0.f;
                    lsum[r] += pv;
                    scr[(quad * 4 + r) * 40 + jt * 16 + l16] = f2bu(pv);
                }
            const bf16x8 pa = *(const bf16x8*)(scr + l16 * 40 + quad * 8);
#pragma unroll
            for (int ft = 0; ft < 4; ft++) {
                const int f = ft * 16 + l16, gn = c * 8 + ch * 4 + quad;
                const bf16x8 bv = *(const bf16x8*)(slab2 + f * 512 + ((gn ^ f) << 3));
                oacc[ft] = MFMA16(pa, bv, oacc[ft]);
            }
        }
    }
#pragma unroll
    for (int r = 0; r < 4; r++) {
        lsum[r] += __shfl_xor(lsum[r], 1);
        lsum[r] += __shfl_xor(lsum[r], 2);
        lsum[r] += __shfl_xor(lsum[r], 4);
        lsum[r] += __shfl_xor(lsum[r], 8);
    }

    // out2 = P@z1/l + z1(own); fused projection + BN1 partials
    float s1a[4] = {0.f, 0.f, 0.f, 0.f}, s2a[4] = {0.f, 0.f, 0.f, 0.f};
    f32x4 inv;
#pragma unroll
    for (int r = 0; r < 4; r++) inv[r] = __builtin_amdgcn_rcpf(lsum[r] * me);
#pragma unroll
    for (int ft = 0; ft < 4; ft++)
#pragma unroll
        for (int r = 0; r < 4; r++) {
            const int i = rowbase + quad * 4 + r;
            const int f = ft * 16 + l16;
            const float o1 = bf2f(slab2[f * 512 + (((i >> 3) ^ f) << 3) + (i & 7)]);
            oacc[ft][r] = oacc[ft][r] * inv[r] + o1;
        }
    // a1 = z1 A-frag (from z1T slab, scalar gather)
    bf16x8 a1[2], a2[2];
    const int irow = rowbase + l16;
#pragma unroll
    for (int h = 0; h < 2; h++)
#pragma unroll
        for (int j = 0; j < 8; j++) {
            const int f = h * 32 + quad * 8 + j;
            const u16 raw = slab2[f * 512 + (((irow >> 3) ^ f) << 3) + (irow & 7)];
            a1[h][j] = __builtin_bit_cast(__bf16, raw);
        }
    // a2 = out2 A-frag via per-wave scratch
#pragma unroll
    for (int h = 0; h < 2; h++) {
#pragma unroll
        for (int ftl = 0; ftl < 2; ftl++)
#pragma unroll
            for (int r = 0; r < 4; r++)
                scr[(quad * 4 + r) * 40 + ftl * 16 + l16] = f2bu(oacc[2 * h + ftl][r]);
        a2[h] = *(const bf16x8*)(scr + l16 * 40 + quad * 8);
    }
    f32x4 pacc[4];
#pragma unroll
    for (int ot = 0; ot < 4; ot++) {
        const int o = ot * 16 + l16;
        const float bias = bf2f(pc[T0B_O + o]) + bf2f(pc[T1B_O + o]);
        pacc[ot] = (f32x4){bias, bias, bias, bias};
    }
#pragma unroll
    for (int h = 0; h < 2; h++)
#pragma unroll
        for (int ot = 0; ot < 4; ot++) {
            const int o = ot * 16 + l16;
            bf16x8 w0f = ld8g(pc + T0W_O + o * 64 + h * 32 + quad * 8);
            bf16x8 w1f = ld8g(pc + T1W_O + o * 64 + h * 32 + quad * 8);
            pacc[ot] = MFMA16(a1[h], w0f, pacc[ot]);
            pacc[ot] = MFMA16(a2[h], w1f, pacc[ot]);
        }
#pragma unroll
    for (int ot = 0; ot < 4; ot++)
#pragma unroll
        for (int r = 0; r < 4; r++) {
            const int i = rowbase + quad * 4 + r;
            const int o = ot * 16 + l16;
            const float v = pacc[ot][r];
            s1a[ot] += v;
            s2a[ot] += v * v;
            opre[(size_t)p * (N1 * FD) + (size_t)i * 64 + o] = f2bu(v);
        }
#pragma unroll
    for (int ot = 0; ot < 4; ot++) {
        s1a[ot] += __shfl_xor(s1a[ot], 16); s1a[ot] += __shfl_xor(s1a[ot], 32);
        s2a[ot] += __shfl_xor(s2a[ot], 16); s2a[ot] += __shfl_xor(s2a[ot], 32);
    }
    if (quad == 0) {
#pragma unroll
        for (int ot = 0; ot < 4; ot++) {
            atomicAdd(&red[ot * 16 + l16], s1a[ot]);
            atomicAdd(&red[64 + ot * 16 + l16], s2a[ot]);
        }
    }
    __syncthreads();
    if (tid < 128) atomicAdd(&stats[128 + tid], red[tid]);
}

// --------------------------- BN1 + lrelu + pooling -> fp32 out -------------
__global__ __launch_bounds__(256) void k_final(const u16* __restrict__ op,
                                               const float* __restrict__ stats,
                                               const u16* __restrict__ pc,
                                               float* __restrict__ out) {
    const int o = blockIdx.x * 256 + threadIdx.x;
    const int f = o & 63, n = (o >> 6) & 255, b = o >> 14;
    const float inv = 1.f / 131072.f;
    const float mu = stats[128 + f] * inv;
    const float var = fmaxf(stats[192 + f] * inv - mu * mu, 0.f);
    const float rs = rsqrtf(var + 1e-5f);
    const float scale = rs * bf2f(pc[B1W_O + f]);
    const float shift = bf2f(pc[B1B_O + f]) - mu * scale;
    float acc = 0.f;
    for (int l = 0; l < 16; l++) {
        const size_t pb = (size_t)(b * 16 + l) * N1 * FD;
#pragma unroll
        for (int m = 0; m < 2; m++) {
            float v = bf2f(op[pb + (size_t)(m * 256 + n) * 64 + f]);
            v = v * scale + shift;
            acc += (v > 0.f ? v : 0.01f * v);
        }
    }
    out[o] = acc * (1.f / 32.f);
}

// ---------------------------------------------------------------------------
extern "C" void kernel_launch(void* const* d_in, const int* in_sizes, int n_in,
                              void* d_out, int out_size, void* d_ws, size_t ws_size,
                              hipStream_t stream) {
    char* ws = (char*)d_ws;
    size_t off = 0;
    auto alloc = [&](size_t bytes) { void* pp = ws + off; off += (bytes + 255) & ~(size_t)255; return pp; };
    u16* y = (u16*)alloc((size_t)Y_ELEMS * 2);
    u16* z1img = (u16*)alloc((size_t)NB * 32768 * 2);
    u16* opre = (u16*)alloc((size_t)NB * N1 * FD * 2);
    u16* pc = (u16*)alloc(P_TOT * 2);
    float* stats = (float*)alloc(256 * 4);
    int* flag = (int*)alloc(256);
    float* out = (float*)d_out;

    k_prep<<<50, 256, 0, stream>>>(d_in[1], d_in[2], d_in[3], d_in[4], d_in[5],
                                   d_in[6], d_in[7], d_in[8], d_in[9], d_in[10],
                                   flag, pc, stats);
    k_y<<<BSZ * SNUM, 256, 0, stream>>>(d_in[0], flag, pc, y, stats);
    k_h1<<<2 * NB, 1024, 0, stream>>>(y, stats, pc, z1img);
    k_h2<<<2 * NB, 1024, 0, stream>>>(y, z1img, stats, pc, opre);
    k_final<<<1024, 256, 0, stream>>>(opre, stats, pc, out);
}

// Round 9
// 201.471 us; speedup vs baseline: 1.2342x; 1.0436x over previous
//
#include <hip/hip_runtime.h>

// ---------------------------------------------------------------------------
// GraphConvpoolMPNN fused rewrite. bs=16,S=17,N=256,F=64,MW=2 -> 256 windows,
// N1=512. adj2@xb == adj@(adj@xb); scores recomputed per hop. Two hop
// kernels, 1024 thr / 16 waves / 16 rows per wave / 2 WGs per window (R16
// geometry: no spill AND 4 waves/SIMD). R17: kill the LDS-pipe bottleneck.
// R16 PMC arithmetic: per (c,ch) iter each wave issued 9 ds_read_b128 + 8
// ds_write_b16 ~ 154 LDS cycles; x16 waves x16 iters x2 WGs/CU ~ 33us =
// the measured k_h2 duration (no pipe >50% otherwise). The scr P-transpose
// round-trip (8 writes + 1 read/iter) was 38% of that. Fix (in-register
// P-transpose, T12-style): (a) SWAPPED score MFMA S^T = mfma(b,a) - bitwise
// identical products; (b) sigma-PERMUTED b-frag rows rj = colbase + (l16&3)
// + (l16>>2)*8 + m*4 -> lane (l16,q) ends up holding columns q*8+m*4+r of
// its OWN row l16 = exactly the PV A-frag layout; f2bu-pack in registers
// (bit-identical pv values), zero LDS, zero cross-lane. (c) slab1 swizzle
// retuned to fsw(n)=(n&3)|(((n>>3)&1)<<2) so the permuted row set stays
// 2-way (free) on banks; all slab1 users updated. (d) lsum becomes per-lane
// scalar (own row), reduced once per kernel (2 shfl_xor + 4 shfl for the
// epilogue inv). LDS/iter: 154 -> 96 cyc (-38%).
// Spill tripwire: WRITE > 30MB on either hop.
// Pipeline: k_prep -> k_y (x@W^T + BN0 stats) -> k_h1 (scores/softmax/hop1
//   -> z1T image) -> k_h2 (scores/softmax/hop2/projection + BN1 stats)
//   -> k_final (BN1 + lrelu + mean).
// ---------------------------------------------------------------------------

typedef unsigned short u16;
typedef __bf16 bf16x8 __attribute__((ext_vector_type(8)));
typedef float f32x4 __attribute__((ext_vector_type(4)));
typedef unsigned int u32x4 __attribute__((ext_vector_type(4)));

#define MFMA16(a, b, c) __builtin_amdgcn_mfma_f32_16x16x32_bf16(a, b, c, 0, 0, 0)

#define BSZ 16
#define SNUM 17
#define FD 64
#define NB 256
#define N1 512
#define SL_ELEMS 16384
#define Y_ELEMS (BSZ * SNUM * SL_ELEMS)

// canonical param buffer offsets (u16 elements)
#define WM_O 0
#define BM_O 4096
#define B0W_O 4160
#define B0B_O 4224
#define T0W_O 4288
#define T0B_O 8384
#define T1W_O 8448
#define T1B_O 12544
#define B1W_O 12608
#define B1B_O 12672
#define P_TOT 12736

// hop-kernel LDS map (u16 units): slab1 [512][64] fsw-XOR, slab2 [64][512]
// XOR(f), red 128 floats (256 u16), scr 16 waves x (16 rows x 40)
#define SLAB2_O 32768
#define RED_O 65536
#define SCR_O 65792
#define LDS_U16 (SCR_O + 16 * 640)  // 76,032 u16 = 152,064 B -> 1 WG/CU

__device__ __forceinline__ float bf2f(u16 u) {
    union { unsigned int i; float f; } v;
    v.i = ((unsigned int)u) << 16;
    return v.f;
}
__device__ __forceinline__ u16 f2bu(float f) {  // RNE via HW cvt
    __bf16 h = (__bf16)f;
    return __builtin_bit_cast(u16, h);
}
__device__ __forceinline__ u16 f2bf(float f) {  // manual RNE (canon path)
    unsigned int u = __builtin_bit_cast(unsigned int, f);
    unsigned int r = (u + 0x7fffu + ((u >> 16) & 1u)) >> 16;
    return (u16)r;
}
__device__ __forceinline__ bf16x8 ld8g(const u16* p) {
    return __builtin_bit_cast(bf16x8, *reinterpret_cast<const u32x4*>(p));
}
// slab1 bank swizzle: 8 values, 2-way on both the a-frag pattern (16
// consecutive rows) and the sigma-permuted b-frag pattern {q*8+m*4+r}.
__device__ __forceinline__ int fsw(int n) {
    return (n & 3) | ((n >> 1) & 4);
}

// ---------------- prep: dtype detect + canon params + zero stats -----------
__global__ __launch_bounds__(256) void k_prep(
    const void* p0, const void* p1, const void* p2, const void* p3,
    const void* p4, const void* p5, const void* p6, const void* p7,
    const void* p8, const void* p9, int* __restrict__ flagOut,
    u16* __restrict__ pc, float* __restrict__ stats) {
    const int tid = threadIdx.x, lane = tid & 63;
    int z = 0, bc = 0;
    const unsigned int* w = (const unsigned int*)p0;
    for (int i = lane; i < 2048; i += 64) {
        const unsigned int v = w[i];
        z += ((v & 0xffffu) == 0u);
        bc += (v >> 14) & 1;
    }
#pragma unroll
    for (int o = 1; o < 64; o <<= 1) {
        z += __shfl_xor(z, o);
        bc += __shfl_xor(bc, o);
    }
    const int flag = (z > 1024 || bc > 256) ? 1 : 0;
    if (blockIdx.x == 0) {
        if (tid == 0) *flagOut = flag;
        if (tid < 256) stats[tid] = 0.f;
    }
    const int i = blockIdx.x * 256 + tid;
    if (i >= P_TOT) return;
    const void* src;
    int si;
    if (i < BM_O)        { src = p0; si = i; }
    else if (i < B0W_O)  { src = p1; si = i - BM_O; }
    else if (i < B0B_O)  { src = p2; si = i - B0W_O; }
    else if (i < T0W_O)  { src = p3; si = i - B0B_O; }
    else if (i < T0B_O)  { src = p4; si = i - T0W_O; }
    else if (i < T1W_O)  { src = p5; si = i - T0B_O; }
    else if (i < T1B_O)  { src = p6; si = i - T1W_O; }
    else if (i < B1W_O)  { src = p7; si = i - T1B_O; }
    else if (i < B1B_O)  { src = p8; si = i - B1W_O; }
    else                 { src = p9; si = i - B1B_O; }
    pc[i] = flag ? f2bf(((const float*)src)[si]) : ((const u16*)src)[si];
}

// ------------------- y = x @ W^T + b  (+ fused BN0 stats) ------------------
__global__ __launch_bounds__(256) void k_y(const void* __restrict__ xv,
                                           const int* __restrict__ flag,
                                           const u16* __restrict__ pc,
                                           u16* __restrict__ y,
                                           float* __restrict__ gstats) {
    const int slice = blockIdx.x;  // 272
    const int tid = threadIdx.x, wave = tid >> 6, lane = tid & 63;
    const int quad = lane >> 4, l16 = lane & 15;
    __shared__ float red[128];
    if (tid < 128) red[tid] = 0.f;
    const int isf32 = *flag;

    f32x4 acc[4][4];
#pragma unroll
    for (int i = 0; i < 4; i++)
#pragma unroll
        for (int j = 0; j < 4; j++) acc[i][j] = (f32x4){0.f, 0.f, 0.f, 0.f};

    bf16x8 bfr[4][2];
#pragma unroll
    for (int nt = 0; nt < 4; nt++)
#pragma unroll
        for (int kh = 0; kh < 2; kh++)
            bfr[nt][kh] = ld8g(pc + WM_O + (nt * 16 + l16) * 64 + kh * 32 + quad * 8);

    const float* xf = (const float*)xv + (size_t)slice * SL_ELEMS;
    const u16* xh = (const u16*)xv + (size_t)slice * SL_ELEMS;

#pragma unroll
    for (int mt = 0; mt < 4; mt++) {
        const int row = wave * 64 + mt * 16 + l16;
        bf16x8 a0, a1;
        if (isf32) {
            const float* r0 = xf + row * 64 + quad * 8;
            f32x4 v0 = *(const f32x4*)r0;
            f32x4 v1 = *(const f32x4*)(r0 + 4);
            f32x4 v2 = *(const f32x4*)(r0 + 32);
            f32x4 v3 = *(const f32x4*)(r0 + 36);
#pragma unroll
            for (int j = 0; j < 4; j++) {
                a0[j] = (__bf16)v0[j]; a0[4 + j] = (__bf16)v1[j];
                a1[j] = (__bf16)v2[j]; a1[4 + j] = (__bf16)v3[j];
            }
        } else {
            a0 = ld8g(xh + row * 64 + quad * 8);
            a1 = ld8g(xh + row * 64 + 32 + quad * 8);
        }
#pragma unroll
        for (int nt = 0; nt < 4; nt++)
            acc[mt][nt] = MFMA16(a1, bfr[nt][1], MFMA16(a0, bfr[nt][0], acc[mt][nt]));
    }

    u16* ys = y + (size_t)slice * SL_ELEMS;
    float s1[4] = {0.f, 0.f, 0.f, 0.f}, s2[4] = {0.f, 0.f, 0.f, 0.f};
#pragma unroll
    for (int nt = 0; nt < 4; nt++) {
        const int col = nt * 16 + l16;
        const float bias = bf2f(pc[BM_O + col]);
#pragma unroll
        for (int mt = 0; mt < 4; mt++)
#pragma unroll
            for (int r = 0; r < 4; r++) {
                const int row = wave * 64 + mt * 16 + quad * 4 + r;
                const float v = acc[mt][nt][r] + bias;
                ys[row * 64 + col] = f2bu(v);
                s1[nt] += v;
                s2[nt] += v * v;
            }
        s1[nt] += __shfl_xor(s1[nt], 16); s1[nt] += __shfl_xor(s1[nt], 32);
        s2[nt] += __shfl_xor(s2[nt], 16); s2[nt] += __shfl_xor(s2[nt], 32);
    }
    __syncthreads();
    if (quad == 0) {
#pragma unroll
        for (int nt = 0; nt < 4; nt++) {
            atomicAdd(&red[nt * 16 + l16], s1[nt]);
            atomicAdd(&red[64 + nt * 16 + l16], s2[nt]);
        }
    }
    __syncthreads();
    const int s = slice % SNUM;
    const float wgt = (s == 0 || s == SNUM - 1) ? 1.f : 2.f;
    if (tid < 128) atomicAdd(&gstats[tid], red[tid] * wgt);
}

// ---- shared staging helper for the hop kernels (1024 thr / 16 waves) ------
__device__ __forceinline__ void stage_slab1(u16* slab1, const u16* ybase,
                                            int tid) {
#pragma unroll
    for (int i = 0; i < 4; i++) {
        const int gid = i * 1024 + tid, n = gid >> 3, g = gid & 7;
        *(u32x4*)(slab1 + n * 64 + ((g ^ fsw(n)) << 3)) =
            *(const u32x4*)(ybase + n * 64 + g * 8);
    }
}

// --------------------------- hop 1: z1 = P@xb/l + xb -----------------------
// 512 WGs = 256 windows x 2 halves; 16 waves x 16 rows (1 subtile each).
// Output: z1T as a raw swizzled slab2 image.
__global__ __launch_bounds__(1024)
__attribute__((amdgpu_waves_per_eu(4, 4)))
void k_h1(const u16* __restrict__ y, const float* __restrict__ stats,
          const u16* __restrict__ pc, u16* __restrict__ z1img) {
    __shared__ u16 lds[LDS_U16];
    u16* slab1 = lds;                       // [n 0..511][g 0..7] fsw-XOR
    u16* slab2 = lds + SLAB2_O;             // xbT then z1T: [f][gn] XOR(f)
    const int tid = threadIdx.x, w = tid >> 6, lane = tid & 63;
    const int quad = lane >> 4, l16 = lane & 15;
    const int g = blockIdx.x, p = g >> 1, half = g & 1;
    const int b = p >> 4, l = p & 15;
    const f32x4 ZERO4 = (f32x4){0.f, 0.f, 0.f, 0.f};

    // BN0 affine constants (per thread channel fme, for slab2 build)
    const float cinv = 1.f / 131072.f;
    const int fme = tid & 63;
    float mu0 = stats[fme] * cinv;
    float vr0 = fmaxf(stats[64 + fme] * cinv - mu0 * mu0, 0.f);
    const float scale_f = rsqrtf(vr0 + 1e-5f) * bf2f(pc[B0W_O + fme]);
    const float shift_f = bf2f(pc[B0B_O + fme]) - mu0 * scale_f;

    const u16* ybase = y + (size_t)(b * SNUM + l) * SL_ELEMS;
    stage_slab1(slab1, ybase, tid);
    __syncthreads();

    // build slab2 = xbT = BN0(nf) transposed, bf16
#pragma unroll
    for (int i = 0; i < 4; i++) {
        const int gn = (tid >> 6) + i * 16;
        union { u16 u[8]; u32x4 v; } pk;
#pragma unroll
        for (int j = 0; j < 8; j++) {
            const int n = gn * 8 + j;
            const u16 raw = slab1[n * 64 + (((fme >> 3) ^ fsw(n)) << 3) + (fme & 7)];
            pk.u[j] = f2bu(bf2f(raw) * scale_f + shift_f);
        }
        *(u32x4*)(slab2 + fme * 512 + ((gn ^ fme) << 3)) = pk.v;
    }
    __syncthreads();

    // hoist nf A-frags for this wave's 16 rows (single subtile)
    const int rowbase = half * 256 + w * 16;
    bf16x8 a[2];
#pragma unroll
    for (int h = 0; h < 2; h++) {
        const int row = rowbase + l16;
        a[h] = *(const bf16x8*)(slab1 + row * 64 + (((h * 4 + quad) ^ fsw(row)) << 3));
    }

    // decay-mask fold: lsum holds mf-scaled values; boundary+final
    // wave-uniform rescale reconstructs exact denominator.
    const float mb = (half == 0) ? 0.7f : (1.0f / 0.7f);
    const float me = (half == 0) ? (1.0f / 0.7f) : 1.0f;

    f32x4 oacc[4];
    float lsum = 0.f;
#pragma unroll
    for (int ft = 0; ft < 4; ft++) oacc[ft] = ZERO4;

#pragma unroll 1
    for (int c = 0; c < 8; c++) {
        if (c == 4) lsum *= mb;
        const float lmf = ((half == 1) == (c >= 4)) ? 0.f : -0.5145731728f;
#pragma unroll
        for (int ch = 0; ch < 2; ch++) {
            const int colbase = c * 64 + ch * 32;
            // swapped + sigma-permuted scores: lane (l16,q) gets columns
            // q*8+m*4+r of its OWN row l16 -> PV A-frag layout directly.
            f32x4 S[2];
#pragma unroll
            for (int m = 0; m < 2; m++) {
                const int rj = colbase + (l16 & 3) + ((l16 >> 2) << 3) + m * 4;
                const bf16x8 b0 = *(const bf16x8*)(slab1 + rj * 64 + ((quad ^ fsw(rj)) << 3));
                const bf16x8 b1 = *(const bf16x8*)(slab1 + rj * 64 + (((4 + quad) ^ fsw(rj)) << 3));
                S[m] = MFMA16(b1, a[1], MFMA16(b0, a[0], ZERO4));
            }
            union { u16 u[8]; bf16x8 v; } pkp;
#pragma unroll
            for (int m = 0; m < 2; m++)
#pragma unroll
                for (int r = 0; r < 4; r++) {
                    const float s = S[m][r];
                    const float m2 = s > 0.f ? 1.44269504f : 0.0144269504f;
                    float pv = exp2f(fminf(fmaf(s, m2, lmf), 86.f));
                    if (colbase + quad * 8 + m * 4 + r == rowbase + l16) pv = 0.f;
                    lsum += pv;
                    pkp.u[m * 4 + r] = f2bu(pv);
                }
            const bf16x8 pa = pkp.v;
#pragma unroll
            for (int ft = 0; ft < 4; ft++) {
                const int f = ft * 16 + l16, gn = c * 8 + ch * 4 + quad;
                const bf16x8 bv = *(const bf16x8*)(slab2 + f * 512 + ((gn ^ f) << 3));
                oacc[ft] = MFMA16(pa, bv, oacc[ft]);
            }
        }
    }
    // softmax denominators: reduce own-row partials across quads, then pull
    // the sums for this lane's OUTPUT rows (quad*4+r) via shfl.
    lsum += __shfl_xor(lsum, 16);
    lsum += __shfl_xor(lsum, 32);
    f32x4 inv;
#pragma unroll
    for (int r = 0; r < 4; r++)
        inv[r] = __builtin_amdgcn_rcpf(__shfl(lsum, quad * 4 + r) * me);

    // z1 = P@xb / l + xb(own row)
#pragma unroll
    for (int ft = 0; ft < 4; ft++)
#pragma unroll
        for (int r = 0; r < 4; r++) {
            const int i = rowbase + quad * 4 + r;
            const int f = ft * 16 + l16;
            const float xbv = bf2f(slab2[f * 512 + (((i >> 3) ^ f) << 3) + (i & 7)]);
            oacc[ft][r] = oacc[ft][r] * inv[r] + xbv;
        }
    __syncthreads();  // all waves done reading xbT (bv + xbv)
    // write z1T into slab2 (overwrite xbT)
#pragma unroll
    for (int ft = 0; ft < 4; ft++)
#pragma unroll
        for (int r = 0; r < 4; r++) {
            const int i = rowbase + quad * 4 + r;
            const int f = ft * 16 + l16;
            slab2[f * 512 + (((i >> 3) ^ f) << 3) + (i & 7)] = f2bu(oacc[ft][r]);
        }
    __syncthreads();
    // dump own-half image chunks to global (vector, coalesced):
    // rows gn in [half*32, half*32+32) of row f live at offset
    // ((half*32)^(f&32))*8, length 256 u16.
    {
        const int fr = tid >> 4, seg = tid & 15;
        const int off = (((half * 32) ^ (fr & 32)) << 3) + seg * 16;
        u16* dst = z1img + (size_t)p * 32768 + fr * 512 + off;
        const u16* srcp = slab2 + fr * 512 + off;
        *(u32x4*)(dst) = *(const u32x4*)(srcp);
        *(u32x4*)(dst + 8) = *(const u32x4*)(srcp + 8);
    }
}

// ------ hop 2: out = z1@w0^T + (P@z1/l + z1)@w1^T + b  (+ BN1 stats) -------
__global__ __launch_bounds__(1024)
__attribute__((amdgpu_waves_per_eu(4, 4)))
void k_h2(const u16* __restrict__ y, const u16* __restrict__ z1img,
          float* __restrict__ stats, const u16* __restrict__ pc,
          u16* __restrict__ opre) {
    __shared__ u16 lds[LDS_U16];
    u16* slab1 = lds;                       // nf  [n][g] fsw-XOR
    u16* slab2 = lds + SLAB2_O;             // z1T [f][gn] XOR(f)
    float* red = (float*)(lds + RED_O);
    const int tid = threadIdx.x, w = tid >> 6, lane = tid & 63;
    const int quad = lane >> 4, l16 = lane & 15;
    u16* scr = lds + SCR_O + w * 640;
    const int g = blockIdx.x, p = g >> 1, half = g & 1;
    const int b = p >> 4, l = p & 15;
    const f32x4 ZERO4 = (f32x4){0.f, 0.f, 0.f, 0.f};

    if (tid < 128) red[tid] = 0.f;

    const u16* ybase = y + (size_t)(b * SNUM + l) * SL_ELEMS;
    stage_slab1(slab1, ybase, tid);

    // slab2 <- z1T raw image (block copy, zero address math)
    const u16* zsrc = z1img + (size_t)p * 32768;
#pragma unroll
    for (int i = 0; i < 4; i++) {
        const int gid = i * 1024 + tid;
        *(u32x4*)(slab2 + gid * 8) = *(const u32x4*)(zsrc + gid * 8);
    }
    __syncthreads();

    const int rowbase = half * 256 + w * 16;
    bf16x8 a[2];
#pragma unroll
    for (int h = 0; h < 2; h++) {
        const int row = rowbase + l16;
        a[h] = *(const bf16x8*)(slab1 + row * 64 + (((h * 4 + quad) ^ fsw(row)) << 3));
    }

    const float mb = (half == 0) ? 0.7f : (1.0f / 0.7f);
    const float me = (half == 0) ? (1.0f / 0.7f) : 1.0f;

    f32x4 oacc[4];
    float lsum = 0.f;
#pragma unroll
    for (int ft = 0; ft < 4; ft++) oacc[ft] = ZERO4;

#pragma unroll 1
    for (int c = 0; c < 8; c++) {
        if (c == 4) lsum *= mb;
        const float lmf = ((half == 1) == (c >= 4)) ? 0.f : -0.5145731728f;
#pragma unroll
        for (int ch = 0; ch < 2; ch++) {
            const int colbase = c * 64 + ch * 32;
            f32x4 S[2];
#pragma unroll
            for (int m = 0; m < 2; m++) {
                const int rj = colbase + (l16 & 3) + ((l16 >> 2) << 3) + m * 4;
                const bf16x8 b0 = *(const bf16x8*)(slab1 + rj * 64 + ((quad ^ fsw(rj)) << 3));
                const bf16x8 b1 = *(const bf16x8*)(slab1 + rj * 64 + (((4 + quad) ^ fsw(rj)) << 3));
                S[m] = MFMA16(b1, a[1], MFMA16(b0, a[0], ZERO4));
            }
            union { u16 u[8]; bf16x8 v; } pkp;
#pragma unroll
            for (int m = 0; m < 2; m++)
#pragma unroll
                for (int r = 0; r < 4; r++) {
                    const float s = S[m][r];
                    const float m2 = s > 0.f ? 1.44269504f : 0.0144269504f;
                    float pv = exp2f(fminf(fmaf(s, m2, lmf), 86.f));
                    if (colbase + quad * 8 + m * 4 + r == rowbase + l16) pv = 0.f;
                    lsum += pv;
                    pkp.u[m * 4 + r] = f2bu(pv);
                }
            const bf16x8 pa = pkp.v;
#pragma unroll
            for (int ft = 0; ft < 4; ft++) {
                const int f = ft * 16 + l16, gn = c * 8 + ch * 4 + quad;
                const bf16x8 bv = *(const bf16x8*)(slab2 + f * 512 + ((gn ^ f) << 3));
                oacc[ft] = MFMA16(pa, bv, oacc[ft]);
            }
        }
    }
    lsum += __shfl_xor(lsum, 16);
    lsum += __shfl_xor(lsum, 32);
    f32x4 inv;
#pragma unroll
    for (int r = 0; r < 4; r++)
        inv[r] = __builtin_amdgcn_rcpf(__shfl(lsum, quad * 4 + r) * me);

    // out2 = P@z1/l + z1(own); fused projection + BN1 partials
    float s1a[4] = {0.f, 0.f, 0.f, 0.f}, s2a[4] = {0.f, 0.f, 0.f, 0.f};
#pragma unroll
    for (int ft = 0; ft < 4; ft++)
#pragma unroll
        for (int r = 0; r < 4; r++) {
            const int i = rowbase + quad * 4 + r;
            const int f = ft * 16 + l16;
            const float o1 = bf2f(slab2[f * 512 + (((i >> 3) ^ f) << 3) + (i & 7)]);
            oacc[ft][r] = oacc[ft][r] * inv[r] + o1;
        }
    // a1 = z1 A-frag (from z1T slab, scalar gather)
    bf16x8 a1[2], a2[2];
    const int irow = rowbase + l16;
#pragma unroll
    for (int h = 0; h < 2; h++)
#pragma unroll
        for (int j = 0; j < 8; j++) {
            const int f = h * 32 + quad * 8 + j;
            const u16 raw = slab2[f * 512 + (((irow >> 3) ^ f) << 3) + (irow & 7)];
            a1[h][j] = __builtin_bit_cast(__bf16, raw);
        }
    // a2 = out2 A-frag via per-wave scratch
#pragma unroll
    for (int h = 0; h < 2; h++) {
#pragma unroll
        for (int ftl = 0; ftl < 2; ftl++)
#pragma unroll
            for (int r = 0; r < 4; r++)
                scr[(quad * 4 + r) * 40 + ftl * 16 + l16] = f2bu(oacc[2 * h + ftl][r]);
        a2[h] = *(const bf16x8*)(scr + l16 * 40 + quad * 8);
    }
    f32x4 pacc[4];
#pragma unroll
    for (int ot = 0; ot < 4; ot++) {
        const int o = ot * 16 + l16;
        const float bias = bf2f(pc[T0B_O + o]) + bf2f(pc[T1B_O + o]);
        pacc[ot] = (f32x4){bias, bias, bias, bias};
    }
#pragma unroll
    for (int h = 0; h < 2; h++)
#pragma unroll
        for (int ot = 0; ot < 4; ot++) {
            const int o = ot * 16 + l16;
            bf16x8 w0f = ld8g(pc + T0W_O + o * 64 + h * 32 + quad * 8);
            bf16x8 w1f = ld8g(pc + T1W_O + o * 64 + h * 32 + quad * 8);
            pacc[ot] = MFMA16(a1[h], w0f, pacc[ot]);
            pacc[ot] = MFMA16(a2[h], w1f, pacc[ot]);
        }
#pragma unroll
    for (int ot = 0; ot < 4; ot++)
#pragma unroll
        for (int r = 0; r < 4; r++) {
            const int i = rowbase + quad * 4 + r;
            const int o = ot * 16 + l16;
            const float v = pacc[ot][r];
            s1a[ot] += v;
            s2a[ot] += v * v;
            opre[(size_t)p * (N1 * FD) + (size_t)i * 64 + o] = f2bu(v);
        }
#pragma unroll
    for (int ot = 0; ot < 4; ot++) {
        s1a[ot] += __shfl_xor(s1a[ot], 16); s1a[ot] += __shfl_xor(s1a[ot], 32);
        s2a[ot] += __shfl_xor(s2a[ot], 16); s2a[ot] += __shfl_xor(s2a[ot], 32);
    }
    if (quad == 0) {
#pragma unroll
        for (int ot = 0; ot < 4; ot++) {
            atomicAdd(&red[ot * 16 + l16], s1a[ot]);
            atomicAdd(&red[64 + ot * 16 + l16], s2a[ot]);
        }
    }
    __syncthreads();
    if (tid < 128) atomicAdd(&stats[128 + tid], red[tid]);
}

// --------------------------- BN1 + lrelu + pooling -> fp32 out -------------
__global__ __launch_bounds__(256) void k_final(const u16* __restrict__ op,
                                               const float* __restrict__ stats,
                                               const u16* __restrict__ pc,
                                               float* __restrict__ out) {
    const int o = blockIdx.x * 256 + threadIdx.x;
    const int f = o & 63, n = (o >> 6) & 255, b = o >> 14;
    const float inv = 1.f / 131072.f;
    const float mu = stats[128 + f] * inv;
    const float var = fmaxf(stats[192 + f] * inv - mu * mu, 0.f);
    const float rs = rsqrtf(var + 1e-5f);
    const float scale = rs * bf2f(pc[B1W_O + f]);
    const float shift = bf2f(pc[B1B_O + f]) - mu * scale;
    float acc = 0.f;
    for (int l = 0; l < 16; l++) {
        const size_t pb = (size_t)(b * 16 + l) * N1 * FD;
#pragma unroll
        for (int m = 0; m < 2; m++) {
            float v = bf2f(op[pb + (size_t)(m * 256 + n) * 64 + f]);
            v = v * scale + shift;
            acc += (v > 0.f ? v : 0.01f * v);
        }
    }
    out[o] = acc * (1.f / 32.f);
}

// ---------------------------------------------------------------------------
extern "C" void kernel_launch(void* const* d_in, const int* in_sizes, int n_in,
                              void* d_out, int out_size, void* d_ws, size_t ws_size,
                              hipStream_t stream) {
    char* ws = (char*)d_ws;
    size_t off = 0;
    auto alloc = [&](size_t bytes) { void* pp = ws + off; off += (bytes + 255) & ~(size_t)255; return pp; };
    u16* y = (u16*)alloc((size_t)Y_ELEMS * 2);
    u16* z1img = (u16*)alloc((size_t)NB * 32768 * 2);
    u16* opre = (u16*)alloc((size_t)NB * N1 * FD * 2);
    u16* pc = (u16*)alloc(P_TOT * 2);
    float* stats = (float*)alloc(256 * 4);
    int* flag = (int*)alloc(256);
    float* out = (float*)d_out;

    k_prep<<<50, 256, 0, stream>>>(d_in[1], d_in[2], d_in[3], d_in[4], d_in[5],
                                   d_in[6], d_in[7], d_in[8], d_in[9], d_in[10],
                                   flag, pc, stats);
    k_y<<<BSZ * SNUM, 256, 0, stream>>>(d_in[0], flag, pc, y, stats);
    k_h1<<<2 * NB, 1024, 0, stream>>>(y, stats, pc, z1img);
    k_h2<<<2 * NB, 1024, 0, stream>>>(y, z1img, stats, pc, opre);
    k_final<<<1024, 256, 0, stream>>>(opre, stats, pc, out);
}